// Round 18
// baseline (217.599 us; speedup 1.0000x reference)
//
#include <hip/hip_runtime.h>
#include <hip/hip_bf16.h>
#include <math.h>

// EmbeddingAlignerOT on MI355X.
// R18: fusion attempt 3 — reg-staged A (T14). R8/R17 both failed at ~103us
// with READ-TIME f32->bf16 cvt (32 VALU cvts between lgkmcnt and MFMA every
// K-step). Now: A loaded f32->REGS (4x f32x4/lane), cvt'd + ds_write'd as
// bf16 AFTER the MFMA burst (in its shadow); inner loop = R11's proven pure
// bf16 path (8 ds_read_b128 -> 16 MFMA, zero cvts). B via gload_lds. A-loads
// issued before B so compiler's auto-vmcnt for cvt = vmcnt(2), B DMA keeps
// full-step cover. Same RNE cvt + MFMA order -> absmax bit-identical.
// GEMM2/3, prep (tgt+W), sink, transposes: R16/R17 verbatim.
// Workspace: [0,16M) Kmat | [16M,32M) KTmat | [32M,34M) W_bf -> ua/ub/va/vb
// after gemm1 | [34M,66M) g_bf | [66M,98M) t_bf -> gTv | [98M..) scalars.

typedef __bf16 bf16_t;
typedef __bf16 bf16x8 __attribute__((ext_vector_type(8)));
typedef float  f32x4  __attribute__((ext_vector_type(4)));

#define NBATCH 32
#define NS 512
#define NG 512
#define NH 1024
#define M_REAL 2
#define N_TOT 100

__device__ __forceinline__ void async_copy16(const void* gsrc, void* ldst) {
  __builtin_amdgcn_global_load_lds(
      (__attribute__((address_space(1))) void*)gsrc,
      (__attribute__((address_space(3))) void*)ldst, 16, 0, 0);
}

// ---------- prep: tgt -> g_bf + g2 row norms (blocks 0..16383, 128 thr),
// ----------       W -> W_bf (blocks 16384..17407) ----------
__global__ __launch_bounds__(128) void prep_kernel(const float* __restrict__ g,
                                                   bf16_t* __restrict__ gb,
                                                   float* __restrict__ g2,
                                                   const float* __restrict__ W,
                                                   bf16_t* __restrict__ Wb) {
  if (blockIdx.x >= 16384) {
    int idx = (blockIdx.x - 16384) * 128 + threadIdx.x;  // 8 f32 each
    const float4* p = (const float4*)W + (size_t)idx * 2;
    float4 a = p[0], b = p[1];
    bf16x8 o;
    o[0] = (__bf16)a.x; o[1] = (__bf16)a.y; o[2] = (__bf16)a.z; o[3] = (__bf16)a.w;
    o[4] = (__bf16)b.x; o[5] = (__bf16)b.y; o[6] = (__bf16)b.z; o[7] = (__bf16)b.w;
    ((bf16x8*)Wb)[idx] = o;
    return;
  }
  int row = blockIdx.x;   // B*G rows of length NH
  int t = threadIdx.x;    // 128
  const float* rp = g + (size_t)row * NH + t * 8;
  float4 a = *(const float4*)rp;
  float4 b = *(const float4*)(rp + 4);
  bf16x8 o;
  o[0] = (__bf16)a.x; o[1] = (__bf16)a.y; o[2] = (__bf16)a.z; o[3] = (__bf16)a.w;
  o[4] = (__bf16)b.x; o[5] = (__bf16)b.y; o[6] = (__bf16)b.z; o[7] = (__bf16)b.w;
  ((bf16x8*)(gb + (size_t)row * NH))[t] = o;
  float ss = a.x*a.x + a.y*a.y + a.z*a.z + a.w*a.w
           + b.x*b.x + b.y*b.y + b.z*b.z + b.w*b.w;
  #pragma unroll
  for (int ofs = 32; ofs > 0; ofs >>= 1) ss += __shfl_down(ss, ofs);
  __shared__ float wsum[2];
  if ((t & 63) == 0) wsum[t >> 6] = ss;
  __syncthreads();
  if (t == 0) g2[row] = wsum[0] + wsum[1];
}

// ---------- adjusted weights for BOTH sides in one dispatch ----------
__global__ __launch_bounds__(512) void weights2_kernel(
    const float* __restrict__ s2, const int* __restrict__ smask, float* __restrict__ swv,
    const float* __restrict__ g2, const int* __restrict__ gmask, float* __restrict__ gwv) {
  int which = blockIdx.x >> 5;
  int bb = blockIdx.x & 31, t = threadIdx.x;
  const float* n2 = which ? g2 : s2;
  const int* mask = which ? gmask : smask;
  float* wout = which ? gwv : swv;
  int idx = bb * 512 + t;
  float mag = sqrtf(n2[idx]) + 1e-12f;
  float w = (float)mask[idx] * mag + 1e-12f;
  float ss = w;
  #pragma unroll
  for (int ofs = 32; ofs > 0; ofs >>= 1) ss += __shfl_down(ss, ofs);
  __shared__ float red[8];
  __shared__ float tot;
  if ((t & 63) == 0) red[t >> 6] = ss;
  __syncthreads();
  if (t == 0) {
    float x = 0.f;
    #pragma unroll
    for (int i = 0; i < 8; i++) x += red[i];
    tot = fmaxf(x, 1e-12f);
  }
  __syncthreads();
  wout[idx] = w / tot;
}

// ---------- GEMM1 fused: t = src(fp32) @ W_bf^T + bias, 128x128, BK=32 ----
// Grid 1024 (8x128), 256 thr, 4 waves. Inner loop = R11's bf16 path.
// A: per lane 4x f32x4 global->regs (rows wave*32+(lane>>1), cols
// (lane&1)*16+..), cvt+2x ds_write_b128 AFTER MFMA into bf16 LDS with
// logical chunk c stored at physical c^(row&3) (matches read XOR).
// B: gload_lds, R11 swizzle. One vmcnt(0)+lgkm(0)+barrier per step.
// Epilogue: bias + bf16 t store + fused row-norm atomicAdd -> s2out.
__global__ __launch_bounds__(256) void gemm1r_kernel(
    const float* __restrict__ A, const bf16_t* __restrict__ Bm,
    bf16_t* __restrict__ outp, const float* __restrict__ bias,
    float* __restrict__ s2out) {
  constexpr int K = 1024;
  __shared__ bf16_t lds[2][2][128 * 32];   // 32 KB, bf16 both operands
  const int nwg = gridDim.x;               // 1024
  const int lin = blockIdx.x;
  const int lin2 = (lin & 7) * (nwg >> 3) + (lin >> 3);  // XCD swizzle
  const int bx = lin2 & 7;                 // 8 col tiles
  const int by = lin2 >> 3;                // 128 row tiles; 8 blocks/XCD share
                                           // one A row-panel (L2 reuse)
  const int tid = threadIdx.x, lane = tid & 63, wave = tid >> 6;
  const int wr = wave >> 1, wc = wave & 1;
  const int m0 = by * 128, n0 = bx * 128;

  // A reg-staging coords: lane stages row aRow, 16 f32 at col (lane&1)*16
  const int aRow = wave * 32 + (lane >> 1);
  const float* ap = A + (size_t)(m0 + aRow) * K + (lane & 1) * 16;
  const int c0 = (lane & 1) * 2;                  // logical chunk base
  const int pc0 = (c0 ^ (aRow & 3)) * 8;          // physical chunk (elems)
  const int pc1 = ((c0 + 1) ^ (aRow & 3)) * 8;
  // B staging (R11): 16 rows x 4 chunks per wave-issue
  const int rB16 = lane >> 2;
  const int cB = (((lane & 3) ^ (rB16 & 3))) * 8;

  auto stageB = [&](int kt, int buf) {
    #pragma unroll
    for (int c = 0; c < 2; c++) {
      int rg = (c * 4 + wave) * 16;
      async_copy16(Bm + (size_t)(n0 + rg + rB16) * K + kt + cB,
                   &lds[buf][1][rg * 32]);
    }
  };

  f32x4 ar[4];
  auto loadA = [&](int kt) {
    #pragma unroll
    for (int q = 0; q < 4; q++) ar[q] = *(const f32x4*)(ap + kt + q * 4);
  };
  auto writeA = [&](int buf) {
    bf16x8 w0, w1;
    w0[0] = (__bf16)ar[0][0]; w0[1] = (__bf16)ar[0][1];
    w0[2] = (__bf16)ar[0][2]; w0[3] = (__bf16)ar[0][3];
    w0[4] = (__bf16)ar[1][0]; w0[5] = (__bf16)ar[1][1];
    w0[6] = (__bf16)ar[1][2]; w0[7] = (__bf16)ar[1][3];
    w1[0] = (__bf16)ar[2][0]; w1[1] = (__bf16)ar[2][1];
    w1[2] = (__bf16)ar[2][2]; w1[3] = (__bf16)ar[2][3];
    w1[4] = (__bf16)ar[3][0]; w1[5] = (__bf16)ar[3][1];
    w1[6] = (__bf16)ar[3][2]; w1[7] = (__bf16)ar[3][3];
    *(bf16x8*)&lds[buf][0][aRow * 32 + pc0] = w0;
    *(bf16x8*)&lds[buf][0][aRow * 32 + pc1] = w1;
  };

  f32x4 acc[4][4];
  #pragma unroll
  for (int i = 0; i < 4; i++)
    #pragma unroll
    for (int j = 0; j < 4; j++) { f32x4 z = {0.f, 0.f, 0.f, 0.f}; acc[i][j] = z; }

  // fragment coords (R11)
  const int chF = ((lane >> 4) ^ (lane & 3)) * 8;
  const int rF = lane & 15;

  // prologue: stage tile 0
  loadA(0);
  stageB(0, 0);
  writeA(0);
  asm volatile("s_waitcnt vmcnt(0) lgkmcnt(0)" ::: "memory");
  __builtin_amdgcn_s_barrier();

  for (int T = 0; T < 32; ++T) {
    const int buf = T & 1;
    if (T < 31) {
      loadA((T + 1) * 32);          // 4 vmem -> regs (issued first)
      stageB((T + 1) * 32, buf ^ 1); // 2 vmem DMA (full-step cover)
    }
    bf16x8 af[4], bf[4];
    #pragma unroll
    for (int m = 0; m < 4; m++)
      af[m] = *(const bf16x8*)&lds[buf][0][(wr * 64 + m * 16 + rF) * 32 + chF];
    #pragma unroll
    for (int n = 0; n < 4; n++)
      bf[n] = *(const bf16x8*)&lds[buf][1][(wc * 64 + n * 16 + rF) * 32 + chF];
    #pragma unroll
    for (int m = 0; m < 4; m++)
      #pragma unroll
      for (int n = 0; n < 4; n++)
        acc[m][n] = __builtin_amdgcn_mfma_f32_16x16x32_bf16(af[m], bf[n], acc[m][n], 0, 0, 0);
    if (T < 31) writeA(buf ^ 1);    // cvt+write in MFMA shadow (compiler
                                    // waits vmcnt(2): A regs only, B in flight)
    asm volatile("s_waitcnt vmcnt(0) lgkmcnt(0)" ::: "memory");
    __builtin_amdgcn_s_barrier();   // B DMA + ds_writes visible; bufs swap
  }

  // epilogue: C/D mapping col=lane&15, row=(lane>>4)*4+j
  const int row_base = m0 + wr * 64, col_base = n0 + wc * 64;
  const int r_off = (lane >> 4) * 4, c_off = lane & 15;
  float p[4][4];
  #pragma unroll
  for (int m = 0; m < 4; m++)
    #pragma unroll
    for (int j = 0; j < 4; j++) p[m][j] = 0.f;
  #pragma unroll
  for (int m = 0; m < 4; m++) {
    #pragma unroll
    for (int n = 0; n < 4; n++) {
      int gn = col_base + n * 16 + c_off;
      float bv = bias[gn];
      #pragma unroll
      for (int j = 0; j < 4; j++) {
        int gm = row_base + m * 16 + r_off + j;
        float tv = acc[m][n][j] + bv;
        outp[(size_t)gm * 1024 + gn] = (__bf16)tv;
        p[m][j] += tv * tv;
      }
    }
  }
  __syncthreads();                     // all LDS reads done; reuse lds
  float* lRed = (float*)&lds[0][0][0]; // 128 floats
  #pragma unroll
  for (int m = 0; m < 4; m++)
    #pragma unroll
    for (int j = 0; j < 4; j++) {
      float v = p[m][j];
      v += __shfl_xor(v, 1);
      v += __shfl_xor(v, 2);
      v += __shfl_xor(v, 4);
      v += __shfl_xor(v, 8);
      p[m][j] = v;                     // valid at lanes with (lane&15)==0
    }
  int rl = wr * 64 + (lane >> 4) * 4;
  if (wc == 0 && (lane & 15) == 0) {
    #pragma unroll
    for (int m = 0; m < 4; m++)
      #pragma unroll
      for (int j = 0; j < 4; j++) lRed[rl + m * 16 + j] = p[m][j];
  }
  __syncthreads();
  if (wc == 1 && (lane & 15) == 0) {
    #pragma unroll
    for (int m = 0; m < 4; m++)
      #pragma unroll
      for (int j = 0; j < 4; j++)
        atomicAdd(&s2out[m0 + rl + m * 16 + j], lRed[rl + m * 16 + j] + p[m][j]);
  }
}

// ---------- C = A * B^T, 128x128 tile, BK=32, 4 waves (GEMM2/3) ----------
// Double-buffered K-loop, stage-at-top, counted vmcnt(4), raw barriers,
// chunk-XOR swizzle, XCD-aware bijective block swizzle.
// MODE 1: K = exp(-10*(sqrt(s2+g2-2C)*sw*gw+eps)) bf16 store (batched)
// MODE 2: out = u .* C, fp32 store (batched)
template <int MODE, int GX, int GY>
__global__ __launch_bounds__(256) void gemm_bt_kernel(
    const bf16_t* __restrict__ A, const bf16_t* __restrict__ Bm, int K_len,
    size_t strideAb, size_t strideBb,
    void* __restrict__ outp, size_t strideOb, int ldc,
    const float* __restrict__ s2, const float* __restrict__ g2,
    const float* __restrict__ sw, const float* __restrict__ gw,
    const float* __restrict__ uvec) {
  __shared__ bf16_t lds[2][2][128 * 32];   // [buf][A=0/B=1][row*32+col]
  const int nwg = gridDim.x;
  const int lin = blockIdx.x;
  const int lin2 = (lin & 7) * (nwg >> 3) + (lin >> 3);
  const int bx = lin2 % GX;
  const int by = (lin2 / GX) % GY;
  const int bz = lin2 / (GX * GY);
  const int tid = threadIdx.x, lane = tid & 63, wave = tid >> 6;
  const int wr = wave >> 1, wc = wave & 1;
  const bf16_t* Ab = A + (size_t)bz * strideAb;
  const bf16_t* Bb = Bm + (size_t)bz * strideBb;
  const int m0 = by * 128, n0 = bx * 128;
  const int rA = lane >> 2;
  const int c8s = (((lane & 3) ^ (rA & 3))) * 8;

  auto stage = [&](int kt, int buf) {
    #pragma unroll
    for (int c = 0; c < 2; c++) {
      int rg = (c * 4 + wave) * 16;
      async_copy16(Ab + (size_t)(m0 + rg + rA) * K_len + kt + c8s, &lds[buf][0][rg * 32]);
      async_copy16(Bb + (size_t)(n0 + rg + rA) * K_len + kt + c8s, &lds[buf][1][rg * 32]);
    }
  };

  f32x4 acc[4][4];
  #pragma unroll
  for (int i = 0; i < 4; i++)
    #pragma unroll
    for (int j = 0; j < 4; j++) { f32x4 z = {0.f, 0.f, 0.f, 0.f}; acc[i][j] = z; }

  const int chF = ((lane >> 4) ^ (lane & 3)) * 8;
  const int rF = lane & 15;

  stage(0, 0);
  int bufsel = 0;
  for (int kt = 0; kt < K_len; kt += 32) {
    if (kt + 32 < K_len) {
      stage(kt + 32, bufsel ^ 1);
      asm volatile("s_waitcnt vmcnt(4)" ::: "memory");
    } else {
      asm volatile("s_waitcnt vmcnt(0)" ::: "memory");
    }
    __builtin_amdgcn_s_barrier();
    bf16x8 af[4], bf[4];
    #pragma unroll
    for (int m = 0; m < 4; m++)
      af[m] = *(const bf16x8*)&lds[bufsel][0][(wr * 64 + m * 16 + rF) * 32 + chF];
    #pragma unroll
    for (int n = 0; n < 4; n++)
      bf[n] = *(const bf16x8*)&lds[bufsel][1][(wc * 64 + n * 16 + rF) * 32 + chF];
    #pragma unroll
    for (int m = 0; m < 4; m++)
      #pragma unroll
      for (int n = 0; n < 4; n++)
        acc[m][n] = __builtin_amdgcn_mfma_f32_16x16x32_bf16(af[m], bf[n], acc[m][n], 0, 0, 0);
    __builtin_amdgcn_s_barrier();
    bufsel ^= 1;
  }

  const int bo = bz * 512;
  const int row_base = m0 + wr * 64, col_base = n0 + wc * 64;
  const int r_off = (lane >> 4) * 4, c_off = lane & 15;
  #pragma unroll
  for (int m = 0; m < 4; m++) {
    #pragma unroll
    for (int n = 0; n < 4; n++) {
      #pragma unroll
      for (int j = 0; j < 4; j++) {
        int gm = row_base + m * 16 + r_off + j;
        int gn = col_base + n * 16 + c_off;
        float val = acc[m][n][j];
        if (MODE == 1) {
          float sq = s2[bo + gm] + g2[bo + gn] - 2.0f * val;
          float d = sqrtf(fmaxf(sq, 0.0f));
          float cost = d * sw[bo + gm] * gw[bo + gn] + 1e-12f;
          ((bf16_t*)outp + (size_t)bz * strideOb)[(size_t)gm * ldc + gn] =
              (__bf16)expf(-10.0f * cost);
        } else {
          ((float*)outp + (size_t)bz * strideOb)[(size_t)gm * ldc + gn] =
              uvec[bo + gm] * val;
        }
      }
    }
  }
}

// ---------- wide transpose: out[c][r] = in[r][c] * (SCALE ? v[r] : 1) ----------
template <int SCALE>
__global__ __launch_bounds__(256) void wide_transpose_kernel(
    const bf16_t* __restrict__ in, bf16_t* __restrict__ out,
    const float* __restrict__ vscale, int inRows, int inCols) {
  __shared__ bf16_t tl[32][66];
  size_t base = (size_t)blockIdx.z * inRows * inCols;
  int r0 = blockIdx.y * 32, c0 = blockIdx.x * 64;
  int row = threadIdx.x >> 3, cc8 = (threadIdx.x & 7) * 8;
  *(bf16x8*)&tl[row][cc8] =
      *(const bf16x8*)(in + base + (size_t)(r0 + row) * inCols + c0 + cc8);
  __syncthreads();
  int orow = threadIdx.x >> 2;
  int rq = (threadIdx.x & 3) * 8;
  bf16x8 o;
  if (SCALE) {
    const float* vp = vscale + (size_t)blockIdx.z * inRows + r0 + rq;
    float4 va = *(const float4*)vp;
    float4 vb = *(const float4*)(vp + 4);
    o[0] = (__bf16)((float)tl[rq + 0][orow] * va.x);
    o[1] = (__bf16)((float)tl[rq + 1][orow] * va.y);
    o[2] = (__bf16)((float)tl[rq + 2][orow] * va.z);
    o[3] = (__bf16)((float)tl[rq + 3][orow] * va.w);
    o[4] = (__bf16)((float)tl[rq + 4][orow] * vb.x);
    o[5] = (__bf16)((float)tl[rq + 5][orow] * vb.y);
    o[6] = (__bf16)((float)tl[rq + 6][orow] * vb.z);
    o[7] = (__bf16)((float)tl[rq + 7][orow] * vb.w);
  } else {
    #pragma unroll
    for (int i = 0; i < 8; i++) o[i] = tl[rq + i][orow];
  }
  *(bf16x8*)(out + base + (size_t)(c0 + orow) * inRows + r0 + rq) = o;
}

// ---------- Sinkhorn half-iteration, grid-wide ----------
template <int INIT>
__global__ __launch_bounds__(256) void sink_pass_kernel(
    const bf16_t* __restrict__ Mmat, const float* __restrict__ x,
    const float* __restrict__ w, float* __restrict__ y) {
  const int b = blockIdx.y;
  const int t = threadIdx.x;
  __shared__ float xs[512];
  if (!INIT) {
    ((float2*)xs)[t] = ((const float2*)(x + b * 512))[t];
    __syncthreads();
  }
  const int row = blockIdx.x * 64 + (t >> 2);
  const int seg = t & 3;
  const bf16_t* rp = Mmat + ((size_t)b * 512 + row) * 512;
  float sum = 0.f;
  #pragma unroll
  for (int j = 0; j < 16; j++) {
    bf16x8 kv = *(const bf16x8*)(rp + seg * 8 + j * 32);
    if (INIT) {
      sum += (float)kv[0] + (float)kv[1] + (float)kv[2] + (float)kv[3] +
             (float)kv[4] + (float)kv[5] + (float)kv[6] + (float)kv[7];
    } else {
      const float4* xp = (const float4*)&xs[seg * 8 + j * 32];
      float4 x0 = xp[0], x1 = xp[1];
      sum += (float)kv[0] * x0.x + (float)kv[1] * x0.y + (float)kv[2] * x0.z +
             (float)kv[3] * x0.w + (float)kv[4] * x1.x + (float)kv[5] * x1.y +
             (float)kv[6] * x1.z + (float)kv[7] * x1.w;
    }
  }
  if (INIT) sum *= (1.0f / 512.0f);
  sum += __shfl_xor(sum, 1);
  sum += __shfl_xor(sum, 2);
  if (seg == 0)
    y[b * 512 + row] = powf(w[b * 512 + row] / sum, 10.0f / 10.1f);
}

// ---------- Sinkhorn closed-form extrapolation to iteration 100 ----------
__global__ __launch_bounds__(512) void sink_final_kernel(
    const float* __restrict__ ua, const float* __restrict__ ub,
    const float* __restrict__ va, const float* __restrict__ vb,
    float* __restrict__ u_out, float* __restrict__ v_out, float Gf) {
  const int b = blockIdx.x, t = threadIdx.x, idx = b * 512 + t;
  const float ubv = ub[idx], vbv = vb[idx];
  float su = logf(ubv / ua[idx]);
  float sv = logf(vbv / va[idx]);
  #pragma unroll
  for (int ofs = 32; ofs > 0; ofs >>= 1) {
    su += __shfl_down(su, ofs);
    sv += __shfl_down(sv, ofs);
  }
  __shared__ float r0[8], r1[8];
  __shared__ float mu, mv;
  if ((t & 63) == 0) { r0[t >> 6] = su; r1[t >> 6] = sv; }
  __syncthreads();
  if (t == 0) {
    float a = 0.f, c = 0.f;
    #pragma unroll
    for (int i = 0; i < 8; i++) { a += r0[i]; c += r1[i]; }
    mu = a / 512.f; mv = c / 512.f;
  }
  __syncthreads();
  u_out[idx] = ubv * expf(Gf * mu);
  v_out[idx] = vbv * expf(Gf * mv);
}

extern "C" void kernel_launch(void* const* d_in, const int* in_sizes, int n_in,
                              void* d_out, int out_size, void* d_ws, size_t ws_size,
                              hipStream_t stream) {
  (void)in_sizes; (void)n_in; (void)out_size; (void)ws_size;
  const float* src = (const float*)d_in[0];   // [32,512,1024]
  const float* tgt = (const float*)d_in[1];   // [32,512,1024]
  const int* smask = (const int*)d_in[2];     // [32,512]
  const int* gmask = (const int*)d_in[3];     // [32,512]
  const float* W   = (const float*)d_in[4];   // [1024,1024]
  const float* bias = (const float*)d_in[5];  // [1024]
  float* out = (float*)d_out;                 // [32,512,1024]

  uint8_t* ws = (uint8_t*)d_ws;
  bf16_t* Kmat  = (bf16_t*)(ws + 0);          // 16 MB
  bf16_t* KTmat = (bf16_t*)(ws + 16777216);   // 16 MB
  bf16_t* W_bf  = (bf16_t*)(ws + 33554432);   // 2 MB
  float* ua = (float*)(ws + 33554432);        // overwrite W_bf after gemm1
  float* ub = ua + 16384;
  float* va = ub + 16384;
  float* vb = va + 16384;
  bf16_t* g_bf  = (bf16_t*)(ws + 35651584);   // 32 MB
  bf16_t* t_bf  = (bf16_t*)(ws + 69206016);   // 32 MB
  bf16_t* gTv   = (bf16_t*)(ws + 69206016);   // reuse after gemm2
  float* s2  = (float*)(ws + 102760448);
  float* g2  = s2 + 16384;
  float* swv = g2 + 16384;
  float* gwv = swv + 16384;
  float* uv  = gwv + 16384;
  float* vv  = uv + 16384;

  // 1. prep: tgt->g_bf+g2, W->W_bf; zero s2 for fused-norm atomics
  prep_kernel<<<17408, 128, 0, stream>>>(tgt, g_bf, g2, W, W_bf);
  hipMemsetAsync(s2, 0, 16384 * sizeof(float), stream);

  // 2. t = src(fp32) @ W_bf^T + b + fused row norms -> s2 (reg-staged cvt)
  gemm1r_kernel<<<1024, 256, 0, stream>>>(src, W_bf, t_bf, bias, s2);

  // 3. weights (both sides, one dispatch)
  weights2_kernel<<<64, 512, 0, stream>>>(s2, smask, swv, g2, gmask, gwv);

  // 4. K = exp(-10*cost)  (per batch 512x512, K=1024)
  gemm_bt_kernel<1, 4, 4><<<512, 256, 0, stream>>>(
      t_bf, g_bf, 1024, (size_t)512 * 1024, (size_t)512 * 1024,
      Kmat, (size_t)512 * 512, 512, s2, g2, swv, gwv, nullptr);

  // 5. K^T (wide transpose)
  wide_transpose_kernel<0><<<dim3(8, 16, 32), 256, 0, stream>>>(
      Kmat, KTmat, nullptr, NS, NG);

  // 6. Sinkhorn: 2 real iterations (4 passes) + extrapolation.
  dim3 pg(NS / 64, NBATCH);
  sink_pass_kernel<1><<<pg, 256, 0, stream>>>(Kmat, nullptr, swv, ua);   // u1
  sink_pass_kernel<0><<<pg, 256, 0, stream>>>(KTmat, ua, gwv, va);       // v1
  sink_pass_kernel<0><<<pg, 256, 0, stream>>>(Kmat, va, swv, ub);        // u2
  sink_pass_kernel<0><<<pg, 256, 0, stream>>>(KTmat, ub, gwv, vb);       // v2

  // G = sum_{j=1}^{100-M_REAL} fi^(2j) in double
  double fi2 = (10.0 / 10.1) * (10.0 / 10.1);
  double Gd = 0.0, pd = 1.0;
  for (int j = 0; j < (N_TOT - M_REAL); j++) { pd *= fi2; Gd += pd; }
  sink_final_kernel<<<32, 512, 0, stream>>>(ua, ub, va, vb, uv, vv, (float)Gd);

  // 7. gTv[h][g] = v[g]*g[g][h] (wide transpose + scale)
  wide_transpose_kernel<1><<<dim3(16, 16, 32), 256, 0, stream>>>(
      g_bf, gTv, vv, NG, NH);

  // 8. aligned = u .* (K @ gTv)  (per batch 512x1024, K=512)
  gemm_bt_kernel<2, 8, 4><<<1024, 256, 0, stream>>>(
      Kmat, gTv, 512, (size_t)512 * 512, (size_t)1024 * 512,
      out, (size_t)512 * 1024, 1024, nullptr, nullptr, nullptr, nullptr, uv);
}

// Round 19
// 184.560 us; speedup vs baseline: 1.1790x; 1.1790x over previous
//
#include <hip/hip_runtime.h>
#include <hip/hip_bf16.h>
#include <math.h>

// EmbeddingAlignerOT on MI355X.
// R19: revert to R16 (best: 186us; fusion family R8/R17/R18 all ~103us on
// gemm1 -> dead). One safe shave: GEMM2's epilogue already holds every K
// value -> fold u1's row-sums (sum_g K[s][g]) into it via the proven
// LDS+shfl+atomicAdd pattern (into zeroed Kv), and compute u1 from Kv in
// the v1 pass prologue (INIT=2). Removes the u1 dispatch + 16MB K re-read.
// Workspace (~98.5 MB): [0,32M) s_bf -> K+KT after gemm1 | [32M,34M) W_bf ->
// ua/ub/va/vb | [34M,66M) g_bf | [66M,98M) t_bf -> gTv | [98M..) scalars+Kv.

typedef __bf16 bf16_t;
typedef __bf16 bf16x8 __attribute__((ext_vector_type(8)));
typedef float  f32x4  __attribute__((ext_vector_type(4)));

#define NBATCH 32
#define NS 512
#define NG 512
#define NH 1024
#define M_REAL 2
#define N_TOT 100

__device__ __forceinline__ void async_copy16(const void* gsrc, void* ldst) {
  __builtin_amdgcn_global_load_lds(
      (__attribute__((address_space(1))) void*)gsrc,
      (__attribute__((address_space(3))) void*)ldst, 16, 0, 0);
}

// ---------- fp32 -> bf16 convert, src and W in one dispatch ----------
__global__ __launch_bounds__(256) void cvt2_kernel(const float* __restrict__ a,
                                                   bf16_t* __restrict__ outa, int n8a,
                                                   const float* __restrict__ b,
                                                   bf16_t* __restrict__ outb) {
  int i = blockIdx.x * 256 + threadIdx.x;
  const float* src;
  bf16_t* dst;
  int idx;
  if (i < n8a) { src = a; dst = outa; idx = i; }
  else         { src = b; dst = outb; idx = i - n8a; }
  const float4* p = (const float4*)src + (size_t)idx * 2;
  float4 x = p[0], y = p[1];
  bf16x8 o;
  o[0] = (__bf16)x.x; o[1] = (__bf16)x.y; o[2] = (__bf16)x.z; o[3] = (__bf16)x.w;
  o[4] = (__bf16)y.x; o[5] = (__bf16)y.y; o[6] = (__bf16)y.z; o[7] = (__bf16)y.w;
  ((bf16x8*)dst)[idx] = o;
}

// ---------- target: convert to bf16 + fp32 row norms ----------
__global__ __launch_bounds__(128) void prep_g_kernel(const float* __restrict__ g,
                                                     bf16_t* __restrict__ gb,
                                                     float* __restrict__ g2) {
  int row = blockIdx.x;   // B*G rows of length NH
  int t = threadIdx.x;    // 128
  const float* rp = g + (size_t)row * NH + t * 8;
  float4 a = *(const float4*)rp;
  float4 b = *(const float4*)(rp + 4);
  bf16x8 o;
  o[0] = (__bf16)a.x; o[1] = (__bf16)a.y; o[2] = (__bf16)a.z; o[3] = (__bf16)a.w;
  o[4] = (__bf16)b.x; o[5] = (__bf16)b.y; o[6] = (__bf16)b.z; o[7] = (__bf16)b.w;
  ((bf16x8*)(gb + (size_t)row * NH))[t] = o;
  float ss = a.x*a.x + a.y*a.y + a.z*a.z + a.w*a.w
           + b.x*b.x + b.y*b.y + b.z*b.z + b.w*b.w;
  #pragma unroll
  for (int ofs = 32; ofs > 0; ofs >>= 1) ss += __shfl_down(ss, ofs);
  __shared__ float wsum[2];
  if ((t & 63) == 0) wsum[t >> 6] = ss;
  __syncthreads();
  if (t == 0) g2[row] = wsum[0] + wsum[1];
}

// ---------- adjusted weights for BOTH sides in one dispatch ----------
__global__ __launch_bounds__(512) void weights2_kernel(
    const float* __restrict__ s2, const int* __restrict__ smask, float* __restrict__ swv,
    const float* __restrict__ g2, const int* __restrict__ gmask, float* __restrict__ gwv) {
  int which = blockIdx.x >> 5;
  int bb = blockIdx.x & 31, t = threadIdx.x;
  const float* n2 = which ? g2 : s2;
  const int* mask = which ? gmask : smask;
  float* wout = which ? gwv : swv;
  int idx = bb * 512 + t;
  float mag = sqrtf(n2[idx]) + 1e-12f;
  float w = (float)mask[idx] * mag + 1e-12f;
  float ss = w;
  #pragma unroll
  for (int ofs = 32; ofs > 0; ofs >>= 1) ss += __shfl_down(ss, ofs);
  __shared__ float red[8];
  __shared__ float tot;
  if ((t & 63) == 0) red[t >> 6] = ss;
  __syncthreads();
  if (t == 0) {
    float x = 0.f;
    #pragma unroll
    for (int i = 0; i < 8; i++) x += red[i];
    tot = fmaxf(x, 1e-12f);
  }
  __syncthreads();
  wout[idx] = w / tot;
}

// ---------- GEMM1: t = A @ W^T + bias, 256x256 tile, 8-wave pipeline ----------
// (R16 verbatim: reg-blocked B frags, stage-all-at-top, 1 vmcnt+barrier/tile)
__global__ __launch_bounds__(512) void gemm1_8ph_kernel(
    const bf16_t* __restrict__ A, const bf16_t* __restrict__ Bm,
    bf16_t* __restrict__ outp, const float* __restrict__ bias,
    float* __restrict__ s2out) {
  constexpr int K = 1024;
  __shared__ bf16_t lds[2][2][256 * 64];   // 128 KB
  const int nwg = gridDim.x;               // 256
  const int lin = blockIdx.x;
  const int lin2 = (lin & 7) * (nwg >> 3) + (lin >> 3);  // XCD swizzle
  const int bx = lin2 & 3;
  const int by = lin2 >> 2;
  const int tid = threadIdx.x, lane = tid & 63, w = tid >> 6;  // 8 waves
  const int wr = w >> 2, wc = w & 3;       // 2 x 4 wave grid
  const int m0 = by * 256, n0 = bx * 256;
  const int sRow = lane >> 3;
  const int sc8 = ((lane & 7) ^ sRow) * 8;   // pre-swizzled global chunk
  const int rF = lane & 15;
  const int cx = lane & 7;
  const int ch0 = (((lane >> 4)) ^ cx) * 8;
  const int ch1 = ch0 ^ 32;

  auto stage_all = [&](int tile) {
    const int buf = tile & 1;
    const int kt = tile << 6;
    #pragma unroll
    for (int j = 0; j < 4; j++) {
      int rA = wr * 128 + (4 * wc + j) * 8;
      async_copy16(A + (size_t)(m0 + rA + sRow) * K + kt + sc8,
                   &lds[buf][0][rA * 64]);
      int wB = wr * 2 + (wc & 1);
      int rB = (wc >> 1) * 128 + (4 * wB + j) * 8;
      async_copy16(Bm + (size_t)(n0 + rB + sRow) * K + kt + sc8,
                   &lds[buf][1][rB * 64]);
    }
  };

  f32x4 acc[8][4];
  #pragma unroll
  for (int i = 0; i < 8; i++)
    #pragma unroll
    for (int j = 0; j < 4; j++) { f32x4 z = {0.f, 0.f, 0.f, 0.f}; acc[i][j] = z; }

  stage_all(0);
  asm volatile("s_waitcnt vmcnt(0)" ::: "memory");
  __builtin_amdgcn_s_barrier();

  for (int T = 0; T < 16; ++T) {
    if (T < 15) stage_all(T + 1);
    const bf16_t* lA = &lds[T & 1][0][0];
    const bf16_t* lB = &lds[T & 1][1][0];
    bf16x8 bfr[4][2];
    #pragma unroll
    for (int nc = 0; nc < 4; nc++) {
      int row = (wc * 64 + nc * 16 + rF) * 64;
      bfr[nc][0] = *(const bf16x8*)&lB[row + ch0];
      bfr[nc][1] = *(const bf16x8*)&lB[row + ch1];
    }
    #pragma unroll
    for (int mq = 0; mq < 2; mq++) {
      #pragma unroll
      for (int mf = 0; mf < 4; mf++) {
        int row = (wr * 128 + mq * 64 + mf * 16 + rF) * 64;
        bf16x8 af0 = *(const bf16x8*)&lA[row + ch0];
        bf16x8 af1 = *(const bf16x8*)&lA[row + ch1];
        __builtin_amdgcn_s_setprio(1);
        #pragma unroll
        for (int nc = 0; nc < 4; nc++) {
          acc[mq * 4 + mf][nc] = __builtin_amdgcn_mfma_f32_16x16x32_bf16(
              af0, bfr[nc][0], acc[mq * 4 + mf][nc], 0, 0, 0);
          acc[mq * 4 + mf][nc] = __builtin_amdgcn_mfma_f32_16x16x32_bf16(
              af1, bfr[nc][1], acc[mq * 4 + mf][nc], 0, 0, 0);
        }
        __builtin_amdgcn_s_setprio(0);
      }
    }
    if (T < 15)
      asm volatile("s_waitcnt vmcnt(0)" ::: "memory");
    __builtin_amdgcn_s_barrier();
  }

  const int r_off = (lane >> 4) * 4, c_off = lane & 15;
  float bs[4];
  #pragma unroll
  for (int ni = 0; ni < 4; ni++)
    bs[ni] = bias[n0 + wc * 64 + ni * 16 + c_off];
  float p[8][4];
  #pragma unroll
  for (int mi = 0; mi < 8; mi++)
    #pragma unroll
    for (int j = 0; j < 4; j++) p[mi][j] = 0.f;
  #pragma unroll
  for (int mi = 0; mi < 8; mi++) {
    int gm = m0 + wr * 128 + (mi >> 2) * 64 + (mi & 3) * 16 + r_off;
    #pragma unroll
    for (int ni = 0; ni < 4; ni++) {
      int gn = n0 + wc * 64 + ni * 16 + c_off;
      #pragma unroll
      for (int j = 0; j < 4; j++) {
        float tv = acc[mi][ni][j] + bs[ni];
        outp[(size_t)(gm + j) * 1024 + gn] = (__bf16)tv;
        p[mi][j] += tv * tv;
      }
    }
  }
  #pragma unroll
  for (int mi = 0; mi < 8; mi++) {
    int gm = m0 + wr * 128 + (mi >> 2) * 64 + (mi & 3) * 16 + r_off;
    #pragma unroll
    for (int j = 0; j < 4; j++) {
      float v = p[mi][j];
      v += __shfl_xor(v, 1);
      v += __shfl_xor(v, 2);
      v += __shfl_xor(v, 4);
      v += __shfl_xor(v, 8);
      if ((lane & 15) == 0) atomicAdd(&s2out[gm + j], v);
    }
  }
}

// ---------- C = A * B^T, 128x128 tile, BK=32, 4 waves (GEMM2/3) ----------
// MODE 1: K = exp(-10*cost) bf16 store (batched) + fused row-sums -> rsum
// MODE 2: out = u .* C, fp32 store (batched)
template <int MODE, int GX, int GY>
__global__ __launch_bounds__(256) void gemm_bt_kernel(
    const bf16_t* __restrict__ A, const bf16_t* __restrict__ Bm, int K_len,
    size_t strideAb, size_t strideBb,
    void* __restrict__ outp, size_t strideOb, int ldc,
    const float* __restrict__ s2, const float* __restrict__ g2,
    const float* __restrict__ sw, const float* __restrict__ gw,
    const float* __restrict__ uvec, float* __restrict__ rsum) {
  __shared__ bf16_t lds[2][2][128 * 32];
  const int nwg = gridDim.x;
  const int lin = blockIdx.x;
  const int lin2 = (lin & 7) * (nwg >> 3) + (lin >> 3);
  const int bx = lin2 % GX;
  const int by = (lin2 / GX) % GY;
  const int bz = lin2 / (GX * GY);
  const int tid = threadIdx.x, lane = tid & 63, wave = tid >> 6;
  const int wr = wave >> 1, wc = wave & 1;
  const bf16_t* Ab = A + (size_t)bz * strideAb;
  const bf16_t* Bb = Bm + (size_t)bz * strideBb;
  const int m0 = by * 128, n0 = bx * 128;
  const int rA = lane >> 2;
  const int c8s = (((lane & 3) ^ (rA & 3))) * 8;

  auto stage = [&](int kt, int buf) {
    #pragma unroll
    for (int c = 0; c < 2; c++) {
      int rg = (c * 4 + wave) * 16;
      async_copy16(Ab + (size_t)(m0 + rg + rA) * K_len + kt + c8s, &lds[buf][0][rg * 32]);
      async_copy16(Bb + (size_t)(n0 + rg + rA) * K_len + kt + c8s, &lds[buf][1][rg * 32]);
    }
  };

  f32x4 acc[4][4];
  #pragma unroll
  for (int i = 0; i < 4; i++)
    #pragma unroll
    for (int j = 0; j < 4; j++) { f32x4 z = {0.f, 0.f, 0.f, 0.f}; acc[i][j] = z; }

  const int chF = ((lane >> 4) ^ (lane & 3)) * 8;
  const int rF = lane & 15;

  stage(0, 0);
  int bufsel = 0;
  for (int kt = 0; kt < K_len; kt += 32) {
    if (kt + 32 < K_len) {
      stage(kt + 32, bufsel ^ 1);
      asm volatile("s_waitcnt vmcnt(4)" ::: "memory");
    } else {
      asm volatile("s_waitcnt vmcnt(0)" ::: "memory");
    }
    __builtin_amdgcn_s_barrier();
    bf16x8 af[4], bf[4];
    #pragma unroll
    for (int m = 0; m < 4; m++)
      af[m] = *(const bf16x8*)&lds[bufsel][0][(wr * 64 + m * 16 + rF) * 32 + chF];
    #pragma unroll
    for (int n = 0; n < 4; n++)
      bf[n] = *(const bf16x8*)&lds[bufsel][1][(wc * 64 + n * 16 + rF) * 32 + chF];
    #pragma unroll
    for (int m = 0; m < 4; m++)
      #pragma unroll
      for (int n = 0; n < 4; n++)
        acc[m][n] = __builtin_amdgcn_mfma_f32_16x16x32_bf16(af[m], bf[n], acc[m][n], 0, 0, 0);
    __builtin_amdgcn_s_barrier();
    bufsel ^= 1;
  }

  const int bo = bz * 512;
  const int row_base = m0 + wr * 64, col_base = n0 + wc * 64;
  const int r_off = (lane >> 4) * 4, c_off = lane & 15;
  float p[4][4];
  #pragma unroll
  for (int m = 0; m < 4; m++)
    #pragma unroll
    for (int j = 0; j < 4; j++) p[m][j] = 0.f;

  #pragma unroll
  for (int m = 0; m < 4; m++) {
    #pragma unroll
    for (int n = 0; n < 4; n++) {
      #pragma unroll
      for (int j = 0; j < 4; j++) {
        int gm = row_base + m * 16 + r_off + j;
        int gn = col_base + n * 16 + c_off;
        float val = acc[m][n][j];
        if (MODE == 1) {
          float sq = s2[bo + gm] + g2[bo + gn] - 2.0f * val;
          float d = sqrtf(fmaxf(sq, 0.0f));
          float cost = d * sw[bo + gm] * gw[bo + gn] + 1e-12f;
          bf16_t kb = (__bf16)expf(-10.0f * cost);
          ((bf16_t*)outp + (size_t)bz * strideOb)[(size_t)gm * ldc + gn] = kb;
          p[m][j] += (float)kb;   // row-sum of (bf16-rounded) K
        } else {
          ((float*)outp + (size_t)bz * strideOb)[(size_t)gm * ldc + gn] =
              uvec[bo + gm] * val;
        }
      }
    }
  }

  if (MODE == 1) {
    // reduce row-sums over this block's 128 cols -> atomicAdd rsum[bo+row]
    __syncthreads();
    float* lRed = (float*)&lds[0][0][0];
    #pragma unroll
    for (int m = 0; m < 4; m++)
      #pragma unroll
      for (int j = 0; j < 4; j++) {
        float v = p[m][j];
        v += __shfl_xor(v, 1);
        v += __shfl_xor(v, 2);
        v += __shfl_xor(v, 4);
        v += __shfl_xor(v, 8);
        p[m][j] = v;
      }
    int rl = wr * 64 + (lane >> 4) * 4;
    if (wc == 0 && (lane & 15) == 0) {
      #pragma unroll
      for (int m = 0; m < 4; m++)
        #pragma unroll
        for (int j = 0; j < 4; j++) lRed[rl + m * 16 + j] = p[m][j];
    }
    __syncthreads();
    if (wc == 1 && (lane & 15) == 0) {
      #pragma unroll
      for (int m = 0; m < 4; m++)
        #pragma unroll
        for (int j = 0; j < 4; j++)
          atomicAdd(&rsum[bo + m0 + rl + m * 16 + j], lRed[rl + m * 16 + j] + p[m][j]);
    }
  }
}

// ---------- wide transpose: out[c][r] = in[r][c] * (SCALE ? v[r] : 1) ----------
template <int SCALE>
__global__ __launch_bounds__(256) void wide_transpose_kernel(
    const bf16_t* __restrict__ in, bf16_t* __restrict__ out,
    const float* __restrict__ vscale, int inRows, int inCols) {
  __shared__ bf16_t tl[32][66];
  size_t base = (size_t)blockIdx.z * inRows * inCols;
  int r0 = blockIdx.y * 32, c0 = blockIdx.x * 64;
  int row = threadIdx.x >> 3, cc8 = (threadIdx.x & 7) * 8;
  *(bf16x8*)&tl[row][cc8] =
      *(const bf16x8*)(in + base + (size_t)(r0 + row) * inCols + c0 + cc8);
  __syncthreads();
  int orow = threadIdx.x >> 2;
  int rq = (threadIdx.x & 3) * 8;
  bf16x8 o;
  if (SCALE) {
    const float* vp = vscale + (size_t)blockIdx.z * inRows + r0 + rq;
    float4 va = *(const float4*)vp;
    float4 vb = *(const float4*)(vp + 4);
    o[0] = (__bf16)((float)tl[rq + 0][orow] * va.x);
    o[1] = (__bf16)((float)tl[rq + 1][orow] * va.y);
    o[2] = (__bf16)((float)tl[rq + 2][orow] * va.z);
    o[3] = (__bf16)((float)tl[rq + 3][orow] * va.w);
    o[4] = (__bf16)((float)tl[rq + 4][orow] * vb.x);
    o[5] = (__bf16)((float)tl[rq + 5][orow] * vb.y);
    o[6] = (__bf16)((float)tl[rq + 6][orow] * vb.z);
    o[7] = (__bf16)((float)tl[rq + 7][orow] * vb.w);
  } else {
    #pragma unroll
    for (int i = 0; i < 8; i++) o[i] = tl[rq + i][orow];
  }
  *(bf16x8*)(out + base + (size_t)(c0 + orow) * inRows + r0 + rq) = o;
}

// ---------- Sinkhorn half-iteration, grid-wide ----------
// INIT=0: x = previous iterate. INIT=2: x = Kv row-sums; prologue computes
// u1 = (w2 / (Kv/512))^fi into xs (and writes it to u1out from block x==0).
template <int INIT>
__global__ __launch_bounds__(256) void sink_pass_kernel(
    const bf16_t* __restrict__ Mmat, const float* __restrict__ x,
    const float* __restrict__ w, float* __restrict__ y,
    const float* __restrict__ w2, float* __restrict__ u1out) {
  const int b = blockIdx.y;
  const int t = threadIdx.x;
  const float fi = 10.0f / 10.1f;
  __shared__ float xs[512];
  if (INIT == 2) {
    float2 kv2 = ((const float2*)(x + b * 512))[t];
    float2 sw2 = ((const float2*)(w2 + b * 512))[t];
    float2 u;
    u.x = powf(sw2.x / (kv2.x * (1.0f / 512.0f)), fi);
    u.y = powf(sw2.y / (kv2.y * (1.0f / 512.0f)), fi);
    ((float2*)xs)[t] = u;
    if (blockIdx.x == 0) ((float2*)(u1out + b * 512))[t] = u;
    __syncthreads();
  } else {
    ((float2*)xs)[t] = ((const float2*)(x + b * 512))[t];
    __syncthreads();
  }
  const int row = blockIdx.x * 64 + (t >> 2);
  const int seg = t & 3;
  const bf16_t* rp = Mmat + ((size_t)b * 512 + row) * 512;
  float sum = 0.f;
  #pragma unroll
  for (int j = 0; j < 16; j++) {
    bf16x8 kv = *(const bf16x8*)(rp + seg * 8 + j * 32);
    const float4* xp = (const float4*)&xs[seg * 8 + j * 32];
    float4 x0 = xp[0], x1 = xp[1];
    sum += (float)kv[0] * x0.x + (float)kv[1] * x0.y + (float)kv[2] * x0.z +
           (float)kv[3] * x0.w + (float)kv[4] * x1.x + (float)kv[5] * x1.y +
           (float)kv[6] * x1.z + (float)kv[7] * x1.w;
  }
  sum += __shfl_xor(sum, 1);
  sum += __shfl_xor(sum, 2);
  if (seg == 0)
    y[b * 512 + row] = powf(w[b * 512 + row] / sum, fi);
}

// ---------- Sinkhorn closed-form extrapolation to iteration 100 ----------
__global__ __launch_bounds__(512) void sink_final_kernel(
    const float* __restrict__ ua, const float* __restrict__ ub,
    const float* __restrict__ va, const float* __restrict__ vb,
    float* __restrict__ u_out, float* __restrict__ v_out, float Gf) {
  const int b = blockIdx.x, t = threadIdx.x, idx = b * 512 + t;
  const float ubv = ub[idx], vbv = vb[idx];
  float su = logf(ubv / ua[idx]);
  float sv = logf(vbv / va[idx]);
  #pragma unroll
  for (int ofs = 32; ofs > 0; ofs >>= 1) {
    su += __shfl_down(su, ofs);
    sv += __shfl_down(sv, ofs);
  }
  __shared__ float r0[8], r1[8];
  __shared__ float mu, mv;
  if ((t & 63) == 0) { r0[t >> 6] = su; r1[t >> 6] = sv; }
  __syncthreads();
  if (t == 0) {
    float a = 0.f, c = 0.f;
    #pragma unroll
    for (int i = 0; i < 8; i++) { a += r0[i]; c += r1[i]; }
    mu = a / 512.f; mv = c / 512.f;
  }
  __syncthreads();
  u_out[idx] = ubv * expf(Gf * mu);
  v_out[idx] = vbv * expf(Gf * mv);
}

extern "C" void kernel_launch(void* const* d_in, const int* in_sizes, int n_in,
                              void* d_out, int out_size, void* d_ws, size_t ws_size,
                              hipStream_t stream) {
  (void)in_sizes; (void)n_in; (void)out_size; (void)ws_size;
  const float* src = (const float*)d_in[0];   // [32,512,1024]
  const float* tgt = (const float*)d_in[1];   // [32,512,1024]
  const int* smask = (const int*)d_in[2];     // [32,512]
  const int* gmask = (const int*)d_in[3];     // [32,512]
  const float* W   = (const float*)d_in[4];   // [1024,1024]
  const float* bias = (const float*)d_in[5];  // [1024]
  float* out = (float*)d_out;                 // [32,512,1024]

  uint8_t* ws = (uint8_t*)d_ws;
  bf16_t* s_bf  = (bf16_t*)(ws + 0);          // 32 MB
  bf16_t* Kmat  = (bf16_t*)(ws + 0);          // reuse after gemm1: 16 MB
  bf16_t* KTmat = (bf16_t*)(ws + 16777216);   // 16 MB
  bf16_t* W_bf  = (bf16_t*)(ws + 33554432);   // 2 MB
  float* ua = (float*)(ws + 33554432);        // overwrite W_bf after gemm1
  float* ub = ua + 16384;
  float* va = ub + 16384;
  float* vb = va + 16384;
  bf16_t* g_bf  = (bf16_t*)(ws + 35651584);   // 32 MB
  bf16_t* t_bf  = (bf16_t*)(ws + 69206016);   // 32 MB
  bf16_t* gTv   = (bf16_t*)(ws + 69206016);   // reuse after gemm2
  float* s2  = (float*)(ws + 102760448);
  float* g2  = s2 + 16384;
  float* swv = g2 + 16384;
  float* gwv = swv + 16384;
  float* uv  = gwv + 16384;
  float* vv  = uv + 16384;
  float* Kv  = vv + 16384;                    // [32][512] K row-sums

  // 1. conversions + g norms; zero s2 (fused norms) and Kv (fused row-sums)
  cvt2_kernel<<<8704, 256, 0, stream>>>(src, s_bf, 2097152, W, W_bf);
  prep_g_kernel<<<16384, 128, 0, stream>>>(tgt, g_bf, g2);
  hipMemsetAsync(s2, 0, 16384 * sizeof(float), stream);
  hipMemsetAsync(Kv, 0, 16384 * sizeof(float), stream);

  // 2. t = s @ W^T + b  (M=16384,N=1024,K=1024) + fused row norms -> s2
  gemm1_8ph_kernel<<<256, 512, 0, stream>>>(s_bf, W_bf, t_bf, bias, s2);

  // 3. weights (both sides, one dispatch)
  weights2_kernel<<<64, 512, 0, stream>>>(s2, smask, swv, g2, gmask, gwv);

  // 4. K = exp(-10*cost)  (per batch 512x512, K=1024) + fused row-sums -> Kv
  gemm_bt_kernel<1, 4, 4><<<512, 256, 0, stream>>>(
      t_bf, g_bf, 1024, (size_t)512 * 1024, (size_t)512 * 1024,
      Kmat, (size_t)512 * 512, 512, s2, g2, swv, gwv, nullptr, Kv);

  // 5. K^T (wide transpose)
  wide_transpose_kernel<0><<<dim3(8, 16, 32), 256, 0, stream>>>(
      Kmat, KTmat, nullptr, NS, NG);

  // 6. Sinkhorn: u1 from Kv inside the v1 pass (INIT=2), then u2, v2.
  dim3 pg(NS / 64, NBATCH);
  sink_pass_kernel<2><<<pg, 256, 0, stream>>>(KTmat, Kv, gwv, va, swv, ua);  // u1+v1
  sink_pass_kernel<0><<<pg, 256, 0, stream>>>(Kmat, va, swv, ub, nullptr, nullptr);  // u2
  sink_pass_kernel<0><<<pg, 256, 0, stream>>>(KTmat, ub, gwv, vb, nullptr, nullptr); // v2

  // G = sum_{j=1}^{100-M_REAL} fi^(2j) in double
  double fi2 = (10.0 / 10.1) * (10.0 / 10.1);
  double Gd = 0.0, pd = 1.0;
  for (int j = 0; j < (N_TOT - M_REAL); j++) { pd *= fi2; Gd += pd; }
  sink_final_kernel<<<32, 512, 0, stream>>>(ua, ub, va, vb, uv, vv, (float)Gd);

  // 7. gTv[h][g] = v[g]*g[g][h] (wide transpose + scale)
  wide_transpose_kernel<1><<<dim3(16, 16, 32), 256, 0, stream>>>(
      g_bf, gTv, vv, NG, NH);

  // 8. aligned = u .* (K @ gTv)  (per batch 512x1024, K=512)
  gemm_bt_kernel<2, 8, 4><<<1024, 256, 0, stream>>>(
      Kmat, gTv, 512, (size_t)512 * 512, (size_t)1024 * 512,
      out, (size_t)512 * 1024, 1024, nullptr, nullptr, nullptr, nullptr, uv, nullptr);
}

// Round 20
// 182.480 us; speedup vs baseline: 1.1925x; 1.0114x over previous
//
#include <hip/hip_runtime.h>
#include <hip/hip_bf16.h>
#include <math.h>

// EmbeddingAlignerOT on MI355X.
// R20: GEMM3 moved onto GEMM1's proven 256x256 8-wave template (exact shape
// fit: per batch M=512,N=1024,K=512 -> grid 2x4x32 = 256 blocks = 1/CU,
// 8 K-tiles BK=64). Epilogue: out = u .* acc (fp32). Ascending-k order
// preserved -> bit-identical. Rest: R19 verbatim (184.6us baseline).
// Workspace (~98.5 MB): [0,32M) s_bf -> K+KT after gemm1 | [32M,34M) W_bf ->
// ua/ub/va/vb | [34M,66M) g_bf | [66M,98M) t_bf -> gTv | [98M..) scalars+Kv.

typedef __bf16 bf16_t;
typedef __bf16 bf16x8 __attribute__((ext_vector_type(8)));
typedef float  f32x4  __attribute__((ext_vector_type(4)));

#define NBATCH 32
#define NS 512
#define NG 512
#define NH 1024
#define M_REAL 2
#define N_TOT 100

__device__ __forceinline__ void async_copy16(const void* gsrc, void* ldst) {
  __builtin_amdgcn_global_load_lds(
      (__attribute__((address_space(1))) void*)gsrc,
      (__attribute__((address_space(3))) void*)ldst, 16, 0, 0);
}

// ---------- fp32 -> bf16 convert, src and W in one dispatch ----------
__global__ __launch_bounds__(256) void cvt2_kernel(const float* __restrict__ a,
                                                   bf16_t* __restrict__ outa, int n8a,
                                                   const float* __restrict__ b,
                                                   bf16_t* __restrict__ outb) {
  int i = blockIdx.x * 256 + threadIdx.x;
  const float* src;
  bf16_t* dst;
  int idx;
  if (i < n8a) { src = a; dst = outa; idx = i; }
  else         { src = b; dst = outb; idx = i - n8a; }
  const float4* p = (const float4*)src + (size_t)idx * 2;
  float4 x = p[0], y = p[1];
  bf16x8 o;
  o[0] = (__bf16)x.x; o[1] = (__bf16)x.y; o[2] = (__bf16)x.z; o[3] = (__bf16)x.w;
  o[4] = (__bf16)y.x; o[5] = (__bf16)y.y; o[6] = (__bf16)y.z; o[7] = (__bf16)y.w;
  ((bf16x8*)dst)[idx] = o;
}

// ---------- target: convert to bf16 + fp32 row norms ----------
__global__ __launch_bounds__(128) void prep_g_kernel(const float* __restrict__ g,
                                                     bf16_t* __restrict__ gb,
                                                     float* __restrict__ g2) {
  int row = blockIdx.x;   // B*G rows of length NH
  int t = threadIdx.x;    // 128
  const float* rp = g + (size_t)row * NH + t * 8;
  float4 a = *(const float4*)rp;
  float4 b = *(const float4*)(rp + 4);
  bf16x8 o;
  o[0] = (__bf16)a.x; o[1] = (__bf16)a.y; o[2] = (__bf16)a.z; o[3] = (__bf16)a.w;
  o[4] = (__bf16)b.x; o[5] = (__bf16)b.y; o[6] = (__bf16)b.z; o[7] = (__bf16)b.w;
  ((bf16x8*)(gb + (size_t)row * NH))[t] = o;
  float ss = a.x*a.x + a.y*a.y + a.z*a.z + a.w*a.w
           + b.x*b.x + b.y*b.y + b.z*b.z + b.w*b.w;
  #pragma unroll
  for (int ofs = 32; ofs > 0; ofs >>= 1) ss += __shfl_down(ss, ofs);
  __shared__ float wsum[2];
  if ((t & 63) == 0) wsum[t >> 6] = ss;
  __syncthreads();
  if (t == 0) g2[row] = wsum[0] + wsum[1];
}

// ---------- adjusted weights for BOTH sides in one dispatch ----------
__global__ __launch_bounds__(512) void weights2_kernel(
    const float* __restrict__ s2, const int* __restrict__ smask, float* __restrict__ swv,
    const float* __restrict__ g2, const int* __restrict__ gmask, float* __restrict__ gwv) {
  int which = blockIdx.x >> 5;
  int bb = blockIdx.x & 31, t = threadIdx.x;
  const float* n2 = which ? g2 : s2;
  const int* mask = which ? gmask : smask;
  float* wout = which ? gwv : swv;
  int idx = bb * 512 + t;
  float mag = sqrtf(n2[idx]) + 1e-12f;
  float w = (float)mask[idx] * mag + 1e-12f;
  float ss = w;
  #pragma unroll
  for (int ofs = 32; ofs > 0; ofs >>= 1) ss += __shfl_down(ss, ofs);
  __shared__ float red[8];
  __shared__ float tot;
  if ((t & 63) == 0) red[t >> 6] = ss;
  __syncthreads();
  if (t == 0) {
    float x = 0.f;
    #pragma unroll
    for (int i = 0; i < 8; i++) x += red[i];
    tot = fmaxf(x, 1e-12f);
  }
  __syncthreads();
  wout[idx] = w / tot;
}

// ---------- 256x256-tile 8-wave GEMM template (C = A @ B^T) ----------
// KLEN: K extent (row stride of A and B). MODE 0: gemm1 (bias + bf16 store +
// fused row-norm atomicAdd). MODE 3: gemm3 (u .* acc, fp32 store, batched:
// strides via bz decomposed from the 1-D grid).
template <int MODE, int KLEN, int GX, int GY>
__global__ __launch_bounds__(512) void gemm256_kernel(
    const bf16_t* __restrict__ A, const bf16_t* __restrict__ Bm,
    size_t strideAb, size_t strideBb,
    void* __restrict__ outp, size_t strideOb, int ldc,
    const float* __restrict__ bias, float* __restrict__ s2out,
    const float* __restrict__ uvec) {
  __shared__ bf16_t lds[2][2][256 * 64];   // 128 KB
  const int nwg = gridDim.x;
  const int lin = blockIdx.x;
  const int lin2 = (lin & 7) * (nwg >> 3) + (lin >> 3);  // XCD swizzle
  const int bx = lin2 % GX;
  const int by = (lin2 / GX) % GY;
  const int bz = lin2 / (GX * GY);
  const int tid = threadIdx.x, lane = tid & 63, w = tid >> 6;  // 8 waves
  const int wr = w >> 2, wc = w & 3;       // 2 x 4 wave grid
  const int m0 = by * 256, n0 = bx * 256;
  const bf16_t* Ab = A + (size_t)bz * strideAb;
  const bf16_t* Bb = Bm + (size_t)bz * strideBb;
  const int sRow = lane >> 3;
  const int sc8 = ((lane & 7) ^ sRow) * 8;   // pre-swizzled global chunk
  const int rF = lane & 15;
  const int cx = lane & 7;
  const int ch0 = (((lane >> 4)) ^ cx) * 8;
  const int ch1 = ch0 ^ 32;

  auto stage_all = [&](int tile) {
    const int buf = tile & 1;
    const int kt = tile << 6;
    #pragma unroll
    for (int j = 0; j < 4; j++) {
      int rA = wr * 128 + (4 * wc + j) * 8;
      async_copy16(Ab + (size_t)(m0 + rA + sRow) * KLEN + kt + sc8,
                   &lds[buf][0][rA * 64]);
      int wB = wr * 2 + (wc & 1);
      int rB = (wc >> 1) * 128 + (4 * wB + j) * 8;
      async_copy16(Bb + (size_t)(n0 + rB + sRow) * KLEN + kt + sc8,
                   &lds[buf][1][rB * 64]);
    }
  };

  f32x4 acc[8][4];
  #pragma unroll
  for (int i = 0; i < 8; i++)
    #pragma unroll
    for (int j = 0; j < 4; j++) { f32x4 z = {0.f, 0.f, 0.f, 0.f}; acc[i][j] = z; }

  stage_all(0);
  asm volatile("s_waitcnt vmcnt(0)" ::: "memory");
  __builtin_amdgcn_s_barrier();

  constexpr int NT = KLEN / 64;
  for (int T = 0; T < NT; ++T) {
    if (T < NT - 1) stage_all(T + 1);
    const bf16_t* lA = &lds[T & 1][0][0];
    const bf16_t* lB = &lds[T & 1][1][0];
    bf16x8 bfr[4][2];
    #pragma unroll
    for (int nc = 0; nc < 4; nc++) {
      int row = (wc * 64 + nc * 16 + rF) * 64;
      bfr[nc][0] = *(const bf16x8*)&lB[row + ch0];
      bfr[nc][1] = *(const bf16x8*)&lB[row + ch1];
    }
    #pragma unroll
    for (int mq = 0; mq < 2; mq++) {
      #pragma unroll
      for (int mf = 0; mf < 4; mf++) {
        int row = (wr * 128 + mq * 64 + mf * 16 + rF) * 64;
        bf16x8 af0 = *(const bf16x8*)&lA[row + ch0];
        bf16x8 af1 = *(const bf16x8*)&lA[row + ch1];
        __builtin_amdgcn_s_setprio(1);
        #pragma unroll
        for (int nc = 0; nc < 4; nc++) {
          acc[mq * 4 + mf][nc] = __builtin_amdgcn_mfma_f32_16x16x32_bf16(
              af0, bfr[nc][0], acc[mq * 4 + mf][nc], 0, 0, 0);
          acc[mq * 4 + mf][nc] = __builtin_amdgcn_mfma_f32_16x16x32_bf16(
              af1, bfr[nc][1], acc[mq * 4 + mf][nc], 0, 0, 0);
        }
        __builtin_amdgcn_s_setprio(0);
      }
    }
    if (T < NT - 1)
      asm volatile("s_waitcnt vmcnt(0)" ::: "memory");
    __builtin_amdgcn_s_barrier();
  }

  // epilogue: C/D mapping col=lane&15, row=(lane>>4)*4+j
  const int r_off = (lane >> 4) * 4, c_off = lane & 15;
  if (MODE == 0) {
    float bs[4];
    #pragma unroll
    for (int ni = 0; ni < 4; ni++)
      bs[ni] = bias[n0 + wc * 64 + ni * 16 + c_off];
    float p[8][4];
    #pragma unroll
    for (int mi = 0; mi < 8; mi++)
      #pragma unroll
      for (int j = 0; j < 4; j++) p[mi][j] = 0.f;
    #pragma unroll
    for (int mi = 0; mi < 8; mi++) {
      int gm = m0 + wr * 128 + (mi >> 2) * 64 + (mi & 3) * 16 + r_off;
      #pragma unroll
      for (int ni = 0; ni < 4; ni++) {
        int gn = n0 + wc * 64 + ni * 16 + c_off;
        #pragma unroll
        for (int j = 0; j < 4; j++) {
          float tv = acc[mi][ni][j] + bs[ni];
          ((bf16_t*)outp)[(size_t)(gm + j) * ldc + gn] = (__bf16)tv;
          p[mi][j] += tv * tv;
        }
      }
    }
    #pragma unroll
    for (int mi = 0; mi < 8; mi++) {
      int gm = m0 + wr * 128 + (mi >> 2) * 64 + (mi & 3) * 16 + r_off;
      #pragma unroll
      for (int j = 0; j < 4; j++) {
        float v = p[mi][j];
        v += __shfl_xor(v, 1);
        v += __shfl_xor(v, 2);
        v += __shfl_xor(v, 4);
        v += __shfl_xor(v, 8);
        if ((lane & 15) == 0) atomicAdd(&s2out[gm + j], v);
      }
    }
  } else {
    // MODE 3: out = u .* acc, fp32, batched
    float* ob = (float*)outp + (size_t)bz * strideOb;
    const float* ub = uvec + bz * 512;
    #pragma unroll
    for (int mi = 0; mi < 8; mi++) {
      int gm = m0 + wr * 128 + (mi >> 2) * 64 + (mi & 3) * 16 + r_off;
      #pragma unroll
      for (int j = 0; j < 4; j++) {
        float uval = ub[gm + j];
        #pragma unroll
        for (int ni = 0; ni < 4; ni++) {
          int gn = n0 + wc * 64 + ni * 16 + c_off;
          ob[(size_t)(gm + j) * ldc + gn] = uval * acc[mi][ni][j];
        }
      }
    }
  }
}

// ---------- C = A * B^T, 128x128 tile, BK=32, 4 waves (GEMM2) ----------
// MODE 1: K = exp(-10*cost) bf16 store (batched) + fused row-sums -> rsum
template <int MODE, int GX, int GY>
__global__ __launch_bounds__(256) void gemm_bt_kernel(
    const bf16_t* __restrict__ A, const bf16_t* __restrict__ Bm, int K_len,
    size_t strideAb, size_t strideBb,
    void* __restrict__ outp, size_t strideOb, int ldc,
    const float* __restrict__ s2, const float* __restrict__ g2,
    const float* __restrict__ sw, const float* __restrict__ gw,
    const float* __restrict__ uvec, float* __restrict__ rsum) {
  __shared__ bf16_t lds[2][2][128 * 32];
  const int nwg = gridDim.x;
  const int lin = blockIdx.x;
  const int lin2 = (lin & 7) * (nwg >> 3) + (lin >> 3);
  const int bx = lin2 % GX;
  const int by = (lin2 / GX) % GY;
  const int bz = lin2 / (GX * GY);
  const int tid = threadIdx.x, lane = tid & 63, wave = tid >> 6;
  const int wr = wave >> 1, wc = wave & 1;
  const bf16_t* Ab = A + (size_t)bz * strideAb;
  const bf16_t* Bb = Bm + (size_t)bz * strideBb;
  const int m0 = by * 128, n0 = bx * 128;
  const int rA = lane >> 2;
  const int c8s = (((lane & 3) ^ (rA & 3))) * 8;

  auto stage = [&](int kt, int buf) {
    #pragma unroll
    for (int c = 0; c < 2; c++) {
      int rg = (c * 4 + wave) * 16;
      async_copy16(Ab + (size_t)(m0 + rg + rA) * K_len + kt + c8s, &lds[buf][0][rg * 32]);
      async_copy16(Bb + (size_t)(n0 + rg + rA) * K_len + kt + c8s, &lds[buf][1][rg * 32]);
    }
  };

  f32x4 acc[4][4];
  #pragma unroll
  for (int i = 0; i < 4; i++)
    #pragma unroll
    for (int j = 0; j < 4; j++) { f32x4 z = {0.f, 0.f, 0.f, 0.f}; acc[i][j] = z; }

  const int chF = ((lane >> 4) ^ (lane & 3)) * 8;
  const int rF = lane & 15;

  stage(0, 0);
  int bufsel = 0;
  for (int kt = 0; kt < K_len; kt += 32) {
    if (kt + 32 < K_len) {
      stage(kt + 32, bufsel ^ 1);
      asm volatile("s_waitcnt vmcnt(4)" ::: "memory");
    } else {
      asm volatile("s_waitcnt vmcnt(0)" ::: "memory");
    }
    __builtin_amdgcn_s_barrier();
    bf16x8 af[4], bf[4];
    #pragma unroll
    for (int m = 0; m < 4; m++)
      af[m] = *(const bf16x8*)&lds[bufsel][0][(wr * 64 + m * 16 + rF) * 32 + chF];
    #pragma unroll
    for (int n = 0; n < 4; n++)
      bf[n] = *(const bf16x8*)&lds[bufsel][1][(wc * 64 + n * 16 + rF) * 32 + chF];
    #pragma unroll
    for (int m = 0; m < 4; m++)
      #pragma unroll
      for (int n = 0; n < 4; n++)
        acc[m][n] = __builtin_amdgcn_mfma_f32_16x16x32_bf16(af[m], bf[n], acc[m][n], 0, 0, 0);
    __builtin_amdgcn_s_barrier();
    bufsel ^= 1;
  }

  const int bo = bz * 512;
  const int row_base = m0 + wr * 64, col_base = n0 + wc * 64;
  const int r_off = (lane >> 4) * 4, c_off = lane & 15;
  float p[4][4];
  #pragma unroll
  for (int m = 0; m < 4; m++)
    #pragma unroll
    for (int j = 0; j < 4; j++) p[m][j] = 0.f;

  #pragma unroll
  for (int m = 0; m < 4; m++) {
    #pragma unroll
    for (int n = 0; n < 4; n++) {
      #pragma unroll
      for (int j = 0; j < 4; j++) {
        int gm = row_base + m * 16 + r_off + j;
        int gn = col_base + n * 16 + c_off;
        float val = acc[m][n][j];
        if (MODE == 1) {
          float sq = s2[bo + gm] + g2[bo + gn] - 2.0f * val;
          float d = sqrtf(fmaxf(sq, 0.0f));
          float cost = d * sw[bo + gm] * gw[bo + gn] + 1e-12f;
          bf16_t kb = (__bf16)expf(-10.0f * cost);
          ((bf16_t*)outp + (size_t)bz * strideOb)[(size_t)gm * ldc + gn] = kb;
          p[m][j] += (float)kb;
        } else {
          ((float*)outp + (size_t)bz * strideOb)[(size_t)gm * ldc + gn] =
              uvec[bo + gm] * val;
        }
      }
    }
  }

  if (MODE == 1) {
    __syncthreads();
    float* lRed = (float*)&lds[0][0][0];
    #pragma unroll
    for (int m = 0; m < 4; m++)
      #pragma unroll
      for (int j = 0; j < 4; j++) {
        float v = p[m][j];
        v += __shfl_xor(v, 1);
        v += __shfl_xor(v, 2);
        v += __shfl_xor(v, 4);
        v += __shfl_xor(v, 8);
        p[m][j] = v;
      }
    int rl = wr * 64 + (lane >> 4) * 4;
    if (wc == 0 && (lane & 15) == 0) {
      #pragma unroll
      for (int m = 0; m < 4; m++)
        #pragma unroll
        for (int j = 0; j < 4; j++) lRed[rl + m * 16 + j] = p[m][j];
    }
    __syncthreads();
    if (wc == 1 && (lane & 15) == 0) {
      #pragma unroll
      for (int m = 0; m < 4; m++)
        #pragma unroll
        for (int j = 0; j < 4; j++)
          atomicAdd(&rsum[bo + m0 + rl + m * 16 + j], lRed[rl + m * 16 + j] + p[m][j]);
    }
  }
}

// ---------- wide transpose: out[c][r] = in[r][c] * (SCALE ? v[r] : 1) ----------
template <int SCALE>
__global__ __launch_bounds__(256) void wide_transpose_kernel(
    const bf16_t* __restrict__ in, bf16_t* __restrict__ out,
    const float* __restrict__ vscale, int inRows, int inCols) {
  __shared__ bf16_t tl[32][66];
  size_t base = (size_t)blockIdx.z * inRows * inCols;
  int r0 = blockIdx.y * 32, c0 = blockIdx.x * 64;
  int row = threadIdx.x >> 3, cc8 = (threadIdx.x & 7) * 8;
  *(bf16x8*)&tl[row][cc8] =
      *(const bf16x8*)(in + base + (size_t)(r0 + row) * inCols + c0 + cc8);
  __syncthreads();
  int orow = threadIdx.x >> 2;
  int rq = (threadIdx.x & 3) * 8;
  bf16x8 o;
  if (SCALE) {
    const float* vp = vscale + (size_t)blockIdx.z * inRows + r0 + rq;
    float4 va = *(const float4*)vp;
    float4 vb = *(const float4*)(vp + 4);
    o[0] = (__bf16)((float)tl[rq + 0][orow] * va.x);
    o[1] = (__bf16)((float)tl[rq + 1][orow] * va.y);
    o[2] = (__bf16)((float)tl[rq + 2][orow] * va.z);
    o[3] = (__bf16)((float)tl[rq + 3][orow] * va.w);
    o[4] = (__bf16)((float)tl[rq + 4][orow] * vb.x);
    o[5] = (__bf16)((float)tl[rq + 5][orow] * vb.y);
    o[6] = (__bf16)((float)tl[rq + 6][orow] * vb.z);
    o[7] = (__bf16)((float)tl[rq + 7][orow] * vb.w);
  } else {
    #pragma unroll
    for (int i = 0; i < 8; i++) o[i] = tl[rq + i][orow];
  }
  *(bf16x8*)(out + base + (size_t)(c0 + orow) * inRows + r0 + rq) = o;
}

// ---------- Sinkhorn half-iteration, grid-wide ----------
// INIT=0: x = previous iterate. INIT=2: x = Kv row-sums; prologue computes
// u1 = (w2 / (Kv/512))^fi into xs (and writes it to u1out from block x==0).
template <int INIT>
__global__ __launch_bounds__(256) void sink_pass_kernel(
    const bf16_t* __restrict__ Mmat, const float* __restrict__ x,
    const float* __restrict__ w, float* __restrict__ y,
    const float* __restrict__ w2, float* __restrict__ u1out) {
  const int b = blockIdx.y;
  const int t = threadIdx.x;
  const float fi = 10.0f / 10.1f;
  __shared__ float xs[512];
  if (INIT == 2) {
    float2 kv2 = ((const float2*)(x + b * 512))[t];
    float2 sw2 = ((const float2*)(w2 + b * 512))[t];
    float2 u;
    u.x = powf(sw2.x / (kv2.x * (1.0f / 512.0f)), fi);
    u.y = powf(sw2.y / (kv2.y * (1.0f / 512.0f)), fi);
    ((float2*)xs)[t] = u;
    if (blockIdx.x == 0) ((float2*)(u1out + b * 512))[t] = u;
    __syncthreads();
  } else {
    ((float2*)xs)[t] = ((const float2*)(x + b * 512))[t];
    __syncthreads();
  }
  const int row = blockIdx.x * 64 + (t >> 2);
  const int seg = t & 3;
  const bf16_t* rp = Mmat + ((size_t)b * 512 + row) * 512;
  float sum = 0.f;
  #pragma unroll
  for (int j = 0; j < 16; j++) {
    bf16x8 kv = *(const bf16x8*)(rp + seg * 8 + j * 32);
    const float4* xp = (const float4*)&xs[seg * 8 + j * 32];
    float4 x0 = xp[0], x1 = xp[1];
    sum += (float)kv[0] * x0.x + (float)kv[1] * x0.y + (float)kv[2] * x0.z +
           (float)kv[3] * x0.w + (float)kv[4] * x1.x + (float)kv[5] * x1.y +
           (float)kv[6] * x1.z + (float)kv[7] * x1.w;
  }
  sum += __shfl_xor(sum, 1);
  sum += __shfl_xor(sum, 2);
  if (seg == 0)
    y[b * 512 + row] = powf(w[b * 512 + row] / sum, fi);
}

// ---------- Sinkhorn closed-form extrapolation to iteration 100 ----------
__global__ __launch_bounds__(512) void sink_final_kernel(
    const float* __restrict__ ua, const float* __restrict__ ub,
    const float* __restrict__ va, const float* __restrict__ vb,
    float* __restrict__ u_out, float* __restrict__ v_out, float Gf) {
  const int b = blockIdx.x, t = threadIdx.x, idx = b * 512 + t;
  const float ubv = ub[idx], vbv = vb[idx];
  float su = logf(ubv / ua[idx]);
  float sv = logf(vbv / va[idx]);
  #pragma unroll
  for (int ofs = 32; ofs > 0; ofs >>= 1) {
    su += __shfl_down(su, ofs);
    sv += __shfl_down(sv, ofs);
  }
  __shared__ float r0[8], r1[8];
  __shared__ float mu, mv;
  if ((t & 63) == 0) { r0[t >> 6] = su; r1[t >> 6] = sv; }
  __syncthreads();
  if (t == 0) {
    float a = 0.f, c = 0.f;
    #pragma unroll
    for (int i = 0; i < 8; i++) { a += r0[i]; c += r1[i]; }
    mu = a / 512.f; mv = c / 512.f;
  }
  __syncthreads();
  u_out[idx] = ubv * expf(Gf * mu);
  v_out[idx] = vbv * expf(Gf * mv);
}

extern "C" void kernel_launch(void* const* d_in, const int* in_sizes, int n_in,
                              void* d_out, int out_size, void* d_ws, size_t ws_size,
                              hipStream_t stream) {
  (void)in_sizes; (void)n_in; (void)out_size; (void)ws_size;
  const float* src = (const float*)d_in[0];   // [32,512,1024]
  const float* tgt = (const float*)d_in[1];   // [32,512,1024]
  const int* smask = (const int*)d_in[2];     // [32,512]
  const int* gmask = (const int*)d_in[3];     // [32,512]
  const float* W   = (const float*)d_in[4];   // [1024,1024]
  const float* bias = (const float*)d_in[5];  // [1024]
  float* out = (float*)d_out;                 // [32,512,1024]

  uint8_t* ws = (uint8_t*)d_ws;
  bf16_t* s_bf  = (bf16_t*)(ws + 0);          // 32 MB
  bf16_t* Kmat  = (bf16_t*)(ws + 0);          // reuse after gemm1: 16 MB
  bf16_t* KTmat = (bf16_t*)(ws + 16777216);   // 16 MB
  bf16_t* W_bf  = (bf16_t*)(ws + 33554432);   // 2 MB
  float* ua = (float*)(ws + 33554432);        // overwrite W_bf after gemm1
  float* ub = ua + 16384;
  float* va = ub + 16384;
  float* vb = va + 16384;
  bf16_t* g_bf  = (bf16_t*)(ws + 35651584);   // 32 MB
  bf16_t* t_bf  = (bf16_t*)(ws + 69206016);   // 32 MB
  bf16_t* gTv   = (bf16_t*)(ws + 69206016);   // reuse after gemm2
  float* s2  = (float*)(ws + 102760448);
  float* g2  = s2 + 16384;
  float* swv = g2 + 16384;
  float* gwv = swv + 16384;
  float* uv  = gwv + 16384;
  float* vv  = uv + 16384;
  float* Kv  = vv + 16384;                    // [32][512] K row-sums

  // 1. conversions + g norms; zero s2 (fused norms) and Kv (fused row-sums)
  cvt2_kernel<<<8704, 256, 0, stream>>>(src, s_bf, 2097152, W, W_bf);
  prep_g_kernel<<<16384, 128, 0, stream>>>(tgt, g_bf, g2);
  hipMemsetAsync(s2, 0, 16384 * sizeof(float), stream);
  hipMemsetAsync(Kv, 0, 16384 * sizeof(float), stream);

  // 2. t = s @ W^T + b  (M=16384,N=1024,K=1024) + fused row norms -> s2
  gemm256_kernel<0, 1024, 4, 64><<<256, 512, 0, stream>>>(
      s_bf, W_bf, 0, 0, t_bf, 0, 1024, bias, s2, nullptr);

  // 3. weights (both sides, one dispatch)
  weights2_kernel<<<64, 512, 0, stream>>>(s2, smask, swv, g2, gmask, gwv);

  // 4. K = exp(-10*cost)  (per batch 512x512, K=1024) + fused row-sums -> Kv
  gemm_bt_kernel<1, 4, 4><<<512, 256, 0, stream>>>(
      t_bf, g_bf, 1024, (size_t)512 * 1024, (size_t)512 * 1024,
      Kmat, (size_t)512 * 512, 512, s2, g2, swv, gwv, nullptr, Kv);

  // 5. K^T (wide transpose)
  wide_transpose_kernel<0><<<dim3(8, 16, 32), 256, 0, stream>>>(
      Kmat, KTmat, nullptr, NS, NG);

  // 6. Sinkhorn: u1 from Kv inside the v1 pass (INIT=2), then u2, v2.
  dim3 pg(NS / 64, NBATCH);
  sink_pass_kernel<2><<<pg, 256, 0, stream>>>(KTmat, Kv, gwv, va, swv, ua);  // u1+v1
  sink_pass_kernel<0><<<pg, 256, 0, stream>>>(Kmat, va, swv, ub, nullptr, nullptr);  // u2
  sink_pass_kernel<0><<<pg, 256, 0, stream>>>(KTmat, ub, gwv, vb, nullptr, nullptr); // v2

  // G = sum_{j=1}^{100-M_REAL} fi^(2j) in double
  double fi2 = (10.0 / 10.1) * (10.0 / 10.1);
  double Gd = 0.0, pd = 1.0;
  for (int j = 0; j < (N_TOT - M_REAL); j++) { pd *= fi2; Gd += pd; }
  sink_final_kernel<<<32, 512, 0, stream>>>(ua, ub, va, vb, uv, vv, (float)Gd);

  // 7. gTv[h][g] = v[g]*g[g][h] (wide transpose + scale)
  wide_transpose_kernel<1><<<dim3(16, 16, 32), 256, 0, stream>>>(
      g_bf, gTv, vv, NG, NH);

  // 8. aligned = u .* (K @ gTv)  (per batch M=512,N=1024,K=512), 256x256 tile
  gemm256_kernel<3, 512, 4, 2><<<256, 512, 0, stream>>>(
      Kmat, gTv, (size_t)512 * 512, (size_t)1024 * 512,
      out, (size_t)512 * 1024, 1024, nullptr, nullptr, uv);
}